// Round 6
// baseline (407.950 us; speedup 1.0000x reference)
//
#include <hip/hip_runtime.h>
#include <hip/hip_bf16.h>
#include <stdint.h>

// ---------------------------------------------------------------------------
// TripletAggregateUngated: B=2, N=256, W=128, H=8, D=16
//  K0: weight prep: Wk[kc 16][n 272][8] bf16, WOt2[cc 32][wr 128][8], bcat[272]
//  K1: ONE block per (b, i): e row read once, LN, GEMM vs all 272 cols.
//      V_in -> VinT[b][h][i][d][j], V_out -> VoutU[b][h][i][d][j] (both
//      contiguous 8-B runs from acc). E_in softmax in-block -> Ain.
//      E_out raw (bias only) -> EoutR[b][i][j][h] f32.
//  KT: transpose VoutU[b][h][k][d][j] -> VoutT[b][h][j][d][k] (LDS tile).
//  K2: A_out softmax over k: EoutR + mask -> AoutT[b][h][i][k].
//  K3: einsum batched GEMMs (unchanged, validated).
//  K4: Va @ W_O (unchanged, validated).
// ---------------------------------------------------------------------------

typedef short short8 __attribute__((ext_vector_type(8)));
typedef short short4v __attribute__((ext_vector_type(4)));
typedef float floatx4 __attribute__((ext_vector_type(4)));

#define AS1(p) ((const __attribute__((address_space(1))) void*)(p))
#define AS3(p) ((__attribute__((address_space(3))) void*)(p))

__device__ inline short f2bf(float v) {
    uint32_t u = __builtin_bit_cast(uint32_t, v);
    u += 0x7FFFu + ((u >> 16) & 1u);   // RNE; inputs finite
    return (short)(u >> 16);
}

// ---------------------------------------------------------------------------
// K0: weight/bias prep.
// ---------------------------------------------------------------------------
__global__ __launch_bounds__(128) void k0_prep(const float* __restrict__ WV,
                                               const float* __restrict__ WE,
                                               const float* __restrict__ WO,
                                               short* __restrict__ Wk,
                                               short* __restrict__ WOt2,
                                               const float* __restrict__ bV,
                                               const float* __restrict__ bE,
                                               float* __restrict__ bcat) {
    int bx = blockIdx.x, t = threadIdx.x;
    if (bx < 16) {
        int kc = bx;
        for (int it = 0; it < 17; ++it) {
            int idx = it * 128 + t;          // 0..2175
            int n = idx >> 3, j = idx & 7, k = kc * 8 + j;
            float val = (n < 256) ? WV[k * 256 + n] : WE[k * 16 + (n - 256)];
            Wk[(kc * 272 + n) * 8 + j] = f2bf(val);
        }
    } else if (bx < 48) {
        int cc = bx - 16;
        for (int j = 0; j < 8; ++j) {
            int c = cc * 8 + j;
            WOt2[(cc * 128 + t) * 8 + j] =
                f2bf(WO[((c & 15) * 16 + (c >> 4)) * 128 + t]);
        }
    } else {
        for (int it = 0; it < 3; ++it) {
            int idx = it * 128 + t;
            if (idx < 272)
                bcat[idx] = (idx < 256) ? bV[idx] : bE[idx - 256];
        }
    }
}

// ---------------------------------------------------------------------------
// K1: fused LN + full projection + E_in softmax. Block = (b, i). j = 0..255
// in two 128-row halves (At 32 KB). Granule g of row stored at g ^ (row&15).
// ---------------------------------------------------------------------------
__global__ __launch_bounds__(256, 4) void k1_ln_proj(
    const float* __restrict__ e, const float* __restrict__ ln_g,
    const float* __restrict__ ln_b, const float* __restrict__ mask,
    const short* __restrict__ Wk, const float* __restrict__ bcat,
    short* __restrict__ VinT, short* __restrict__ VoutU,
    short* __restrict__ Ain, float* __restrict__ EoutR) {
    __shared__ short At[128 * 128];   // 32 KB
    __shared__ float maskb[256];
    __shared__ float redm[4][8];
    __shared__ float reds[4][8];

    const int tid = threadIdx.x;
    const int fix = blockIdx.x;       // i
    const int b = blockIdx.y;

    maskb[tid] = mask[((size_t)b * 256 + fix) * 256 + tid];

    const int lane = tid & 63, w = tid >> 6;
    const int ln_ = lane & 15, quad = lane >> 4;
    float vE[16];

    for (int hl = 0; hl < 2; ++hl) {
        if (hl) __syncthreads();   // prior GEMM reads of At done
        // ---- LayerNorm: 4 threads/row, 2 passes of 64 rows ----
        {
            const int rq = tid & 3;
            const int rowi = tid >> 2;
#pragma unroll
            for (int pass = 0; pass < 2; ++pass) {
                int row = pass * 64 + rowi;            // local 0..127
                int j = hl * 128 + row;
                const float* ep = e + (((size_t)b * 256 + fix) * 256 + j) * 128 + rq * 4;
                float4 val[8];
                float s = 0.f, s2 = 0.f;
#pragma unroll
                for (int i = 0; i < 8; ++i) {
                    val[i] = *(const float4*)(ep + i * 16);
                    s += val[i].x + val[i].y + val[i].z + val[i].w;
                    s2 += val[i].x * val[i].x + val[i].y * val[i].y +
                          val[i].z * val[i].z + val[i].w * val[i].w;
                }
                s += __shfl_xor(s, 1); s2 += __shfl_xor(s2, 1);
                s += __shfl_xor(s, 2); s2 += __shfl_xor(s2, 2);
                float mean = s * 0.0078125f;
                float var = s2 * 0.0078125f - mean * mean;
                float rs = rsqrtf(var + 1e-5f);
#pragma unroll
                for (int i = 0; i < 8; ++i) {
                    int col = i * 16 + rq * 4;
                    float4 gg = *(const float4*)(ln_g + col);
                    float4 bb = *(const float4*)(ln_b + col);
                    short4v o;
                    o[0] = f2bf((val[i].x - mean) * rs * gg.x + bb.x);
                    o[1] = f2bf((val[i].y - mean) * rs * gg.y + bb.y);
                    o[2] = f2bf((val[i].z - mean) * rs * gg.z + bb.z);
                    o[3] = f2bf((val[i].w - mean) * rs * gg.w + bb.w);
                    int g = col >> 3;
                    int cp = g ^ (row & 15);
                    int hf4 = (col >> 2) & 1;
                    *(short4v*)&At[row * 128 + cp * 8 + hf4 * 4] = o;
                }
            }
        }
        __syncthreads();

        // ---- V chunks: 4 x 64 cols. Wave w owns local rows w*32..w*32+31.
#pragma unroll
        for (int chunk = 0; chunk < 4; ++chunk) {
            floatx4 acc[2][4] = {};
#pragma unroll
            for (int kk = 0; kk < 4; ++kk) {
                int ckb = kk * 4 + quad;
                int cp = ckb ^ ln_;
                short8 aq[2];
#pragma unroll
                for (int mt = 0; mt < 2; ++mt) {
                    int r = w * 32 + mt * 16 + ln_;
                    aq[mt] = *(const short8*)&At[r * 128 + cp * 8];
                }
                short8 bq[4];
#pragma unroll
                for (int ntl = 0; ntl < 4; ++ntl) {
                    int c = chunk * 64 + ntl * 16 + ln_;
                    bq[ntl] = *(const short8*)(Wk + (ckb * 272 + c) * 8);
                }
#pragma unroll
                for (int mt = 0; mt < 2; ++mt)
#pragma unroll
                    for (int ntl = 0; ntl < 4; ++ntl)
                        acc[mt][ntl] = __builtin_amdgcn_mfma_f32_16x16x32_bf16(
                            aq[mt], bq[ntl], acc[mt][ntl], 0, 0, 0);
            }
#pragma unroll
            for (int ntl = 0; ntl < 4; ++ntl) {
                int c = chunk * 64 + ntl * 16 + ln_;
                float bias = bcat[c];
                int part = c >> 7, cc = c & 127;
                int d = cc >> 3, hh = cc & 7;
                short* dst = part ? VoutU : VinT;
                size_t rowbase = (((size_t)(b * 8 + hh) * 256 + fix) * 16 + d) * 256;
#pragma unroll
                for (int mt = 0; mt < 2; ++mt) {
                    short4v o;
#pragma unroll
                    for (int r = 0; r < 4; ++r) o[r] = f2bf(acc[mt][ntl][r] + bias);
                    *(short4v*)(dst + rowbase + hl * 128 + w * 32 + mt * 16 + quad * 4) = o;
                }
            }
        }

        // ---- E chunk: cols 256..271 (E_in 8 | E_out 8) ----
        {
            floatx4 accE[2] = {};
#pragma unroll
            for (int kk = 0; kk < 4; ++kk) {
                int ckb = kk * 4 + quad;
                int cp = ckb ^ ln_;
                short8 bq = *(const short8*)(Wk + (ckb * 272 + 256 + ln_) * 8);
#pragma unroll
                for (int mt = 0; mt < 2; ++mt) {
                    int r = w * 32 + mt * 16 + ln_;
                    short8 aq = *(const short8*)&At[r * 128 + cp * 8];
                    accE[mt] = __builtin_amdgcn_mfma_f32_16x16x32_bf16(
                        aq, bq, accE[mt], 0, 0, 0);
                }
            }
            float bias = bcat[256 + ln_];
#pragma unroll
            for (int mt = 0; mt < 2; ++mt)
#pragma unroll
                for (int r = 0; r < 4; ++r) {
                    int k = hl * 128 + w * 32 + mt * 16 + quad * 4 + r;
                    vE[hl * 8 + mt * 4 + r] =
                        accE[mt][r] + bias + (ln_ < 8 ? maskb[k] : 0.f);
                }
        }
    }

    // ---- E_in softmax over 256 j (lanes ln_<8); E_out raw store (ln_>=8) ----
    {
        float m = vE[0];
#pragma unroll
        for (int i = 1; i < 16; ++i) m = fmaxf(m, vE[i]);
        m = fmaxf(m, __shfl_xor(m, 16));
        m = fmaxf(m, __shfl_xor(m, 32));
        if (quad == 0 && ln_ < 8) redm[w][ln_] = m;
        __syncthreads();
        int hs = ln_ & 7;
        float bmax = fmaxf(fmaxf(redm[0][hs], redm[1][hs]),
                           fmaxf(redm[2][hs], redm[3][hs]));
        float p[16], s = 0.f;
#pragma unroll
        for (int i = 0; i < 16; ++i) { p[i] = __expf(vE[i] - bmax); s += p[i]; }
        s += __shfl_xor(s, 16);
        s += __shfl_xor(s, 32);
        if (quad == 0 && ln_ < 8) reds[w][ln_] = s;
        __syncthreads();
        float inv = 1.f / (reds[0][hs] + reds[1][hs] + reds[2][hs] + reds[3][hs]);
        if (ln_ < 8) {
            size_t rowbase = (size_t)(b * 8 + ln_) * 65536 + (size_t)fix * 256;
#pragma unroll
            for (int hl = 0; hl < 2; ++hl)
#pragma unroll
                for (int mt = 0; mt < 2; ++mt) {
                    short4v o;
#pragma unroll
                    for (int r = 0; r < 4; ++r)
                        o[r] = f2bf(p[hl * 8 + mt * 4 + r] * inv);
                    *(short4v*)(Ain + rowbase + hl * 128 + w * 32 + mt * 16 + quad * 4) = o;
                }
        } else {
            int h = ln_ - 8;
            size_t base = ((size_t)b * 256 + fix) * 2048;   // [j 256][h 8] f32
#pragma unroll
            for (int hl = 0; hl < 2; ++hl)
#pragma unroll
                for (int mt = 0; mt < 2; ++mt)
#pragma unroll
                    for (int r = 0; r < 4; ++r) {
                        int j = hl * 128 + w * 32 + mt * 16 + quad * 4 + r;
                        EoutR[base + j * 8 + h] = vE[hl * 8 + mt * 4 + r];
                    }
        }
    }
}

// ---------------------------------------------------------------------------
// KT: VoutU[bh][k][d][j] -> VoutT[bh][j][d][k]. Tile: fixed (bh,d), 64k x 64j.
// ---------------------------------------------------------------------------
__global__ __launch_bounds__(256) void kT_transpose(const short* __restrict__ VoutU,
                                                    short* __restrict__ VoutT) {
    __shared__ short L[64 * 68];
    const int t = threadIdx.x;
    const int jt = blockIdx.x;        // 0..3
    const int kt2 = blockIdx.y;       // 0..3
    const int z = blockIdx.z;         // 0..255
    const int bh = z >> 4, d = z & 15;

#pragma unroll
    for (int it = 0; it < 2; ++it) {
        int cid = it * 256 + t;       // 0..511
        int k = cid >> 3, jc = cid & 7;
        short8 v = *(const short8*)(VoutU +
            (((size_t)(bh * 256 + kt2 * 64 + k)) * 16 + d) * 256 + jt * 64 + jc * 8);
        *(short8*)&L[k * 68 + jc * 8] = v;
    }
    __syncthreads();
#pragma unroll
    for (int it = 0; it < 2; ++it) {
        int cid = it * 256 + t;
        int j = cid >> 3, kc = cid & 7;
        short8 o;
#pragma unroll
        for (int s = 0; s < 8; ++s) o[s] = L[(kc * 8 + s) * 68 + j];
        *(short8*)(VoutT +
            (((size_t)(bh * 256 + jt * 64 + j)) * 16 + d) * 256 + kt2 * 64 + kc * 8) = o;
    }
}

// ---------------------------------------------------------------------------
// K2: A_out softmax. Block (b,i): softmax over k of EoutR[b][k][i][h]+mask[b,k,i]
// -> AoutT[b][h][i][k].
// ---------------------------------------------------------------------------
__global__ __launch_bounds__(256) void k2_softmax_out(const float* __restrict__ EoutR,
                                                      const float* __restrict__ mask,
                                                      short* __restrict__ AoutT) {
    __shared__ float redm[4][8];
    __shared__ float reds[4][8];
    int bi = blockIdx.x;
    int b = bi >> 8, i = bi & 255;
    int k = threadIdx.x;
    int wid = k >> 6, lane = k & 63;

    const float* src = EoutR + (((size_t)b * 256 + k) * 256 + i) * 8;
    float4 a0 = *(const float4*)src;
    float4 a1 = *(const float4*)(src + 4);
    float mo = mask[((size_t)b * 256 + k) * 256 + i];
    float v[8] = {a0.x + mo, a0.y + mo, a0.z + mo, a0.w + mo,
                  a1.x + mo, a1.y + mo, a1.z + mo, a1.w + mo};

    float wm[8];
#pragma unroll
    for (int ch = 0; ch < 8; ++ch) {
        float m = v[ch];
#pragma unroll
        for (int off = 1; off < 64; off <<= 1) m = fmaxf(m, __shfl_xor(m, off));
        wm[ch] = m;
    }
    if (lane == 0) {
#pragma unroll
        for (int ch = 0; ch < 8; ++ch) redm[wid][ch] = wm[ch];
    }
    __syncthreads();
    float p[8], ws[8];
#pragma unroll
    for (int ch = 0; ch < 8; ++ch) {
        float bmax = fmaxf(fmaxf(redm[0][ch], redm[1][ch]),
                           fmaxf(redm[2][ch], redm[3][ch]));
        p[ch] = __expf(v[ch] - bmax);
        float s = p[ch];
#pragma unroll
        for (int off = 1; off < 64; off <<= 1) s += __shfl_xor(s, off);
        ws[ch] = s;
    }
    if (lane == 0) {
#pragma unroll
        for (int ch = 0; ch < 8; ++ch) reds[wid][ch] = ws[ch];
    }
    __syncthreads();
#pragma unroll
    for (int ch = 0; ch < 8; ++ch) {
        float inv = 1.f / (reds[0][ch] + reds[1][ch] + reds[2][ch] + reds[3][ch]);
        AoutT[(((size_t)b * 8 + ch) * 256 + i) * 256 + k] = f2bf(p[ch] * inv);
    }
}

// ---------------------------------------------------------------------------
// K3: per (b,h,part): C[i,jd] = sum_k A[i,k] V[jd,k]. 128x128 tile, BK=64 x4.
// ---------------------------------------------------------------------------
__global__ __launch_bounds__(256, 3) void k3_einsum(const short* __restrict__ Ain,
                                                    const short* __restrict__ AoutT,
                                                    const short* __restrict__ VinT,
                                                    const short* __restrict__ VoutT,
                                                    short* __restrict__ VaP2) {
    __shared__ short AB[2048 * 8];  // 32 KB
    const int tid = threadIdx.x, lane = tid & 63, w = tid >> 6;
    const int i0 = blockIdx.x * 128;
    const int jd0 = blockIdx.y * 128;
    const int z = blockIdx.z;
    const int b = z >> 4, part = (z >> 3) & 1, h = z & 7;

    const short* Abase = (part ? AoutT : Ain) + ((size_t)(b * 8 + h)) * 65536 + (size_t)i0 * 256;
    const short* Bbase = (part ? VoutT : VinT) + ((size_t)(b * 8 + h)) * 1048576 + (size_t)jd0 * 256;

    const int ln_ = lane & 15, quad = lane >> 4;
    const int m0 = (w >> 1) * 64, n0 = (w & 1) * 64;
    floatx4 acc[4][4] = {};

    for (int kt = 0; kt < 4; ++kt) {
        if (kt) __syncthreads();
        for (int it = 0; it < 8; ++it) {
            int cid = w * 512 + it * 64 + lane;   // 0..2047
            int isB = cid >> 10;
            int lc = cid & 1023;
            int r = lc >> 3;
            int ck = (lc & 7) ^ (r & 7);
            const short* g = (isB ? Bbase : Abase) + r * 256 + kt * 64 + ck * 8;
            __builtin_amdgcn_global_load_lds(AS1(g), AS3(&AB[cid * 8]), 16, 0, 0);
        }
        __syncthreads();

#pragma unroll
        for (int kk = 0; kk < 2; ++kk) {
            int ckb = kk * 4 + quad;
            short8 aq[4], bq[4];
#pragma unroll
            for (int t = 0; t < 4; ++t) {
                int r = m0 + t * 16 + ln_;
                aq[t] = *(const short8*)&AB[(r * 8 + (ckb ^ (r & 7))) * 8];
            }
#pragma unroll
            for (int t = 0; t < 4; ++t) {
                int r = n0 + t * 16 + ln_;
                bq[t] = *(const short8*)&AB[(1024 + r * 8 + (ckb ^ (r & 7))) * 8];
            }
#pragma unroll
            for (int mt = 0; mt < 4; ++mt)
#pragma unroll
                for (int nt = 0; nt < 4; ++nt)
                    acc[mt][nt] = __builtin_amdgcn_mfma_f32_16x16x32_bf16(aq[mt], bq[nt], acc[mt][nt], 0, 0, 0);
        }
    }

    const int ph = part * 8 + h;
#pragma unroll
    for (int mt = 0; mt < 4; ++mt) {
#pragma unroll
        for (int nt = 0; nt < 4; ++nt) {
            int j = (jd0 + n0 + nt * 16) >> 4;
#pragma unroll
            for (int r = 0; r < 4; ++r) {
                int i = i0 + m0 + mt * 16 + quad * 4 + r;
                size_t m = ((size_t)b * 256 + i) * 256 + j;
                VaP2[((size_t)ph * 131072 + m) * 16 + ln_] = f2bf(acc[mt][nt][r]);
            }
        }
    }
}

// ---------------------------------------------------------------------------
// K4: out[m][w] = sum_c A[m][c] * WOt2[c-chunk][w][8] + bO[w].
// ---------------------------------------------------------------------------
__global__ __launch_bounds__(256, 3) void k4_proj(const short* __restrict__ VaP2,
                                                  const short* __restrict__ WOt2,
                                                  const float* __restrict__ bO,
                                                  float* __restrict__ out) {
    __shared__ short A_s[16384];  // 32 KB
    const int tid = threadIdx.x, lane = tid & 63, w = tid >> 6;
    const size_t m0g = (size_t)blockIdx.x * 128;
    const int ln_ = lane & 15, quad = lane >> 4;
    const int m0 = (w >> 1) * 64, n0 = (w & 1) * 64;
    floatx4 acc[4][4] = {};

    for (int kt = 0; kt < 2; ++kt) {
        if (kt) __syncthreads();
        for (int it = 0; it < 8; ++it) {
            int cid = w * 512 + it * 64 + lane;     // 0..2047
            int p = cid >> 8, rm = cid & 255, half = rm >> 7, m = rm & 127;
            const short* g = VaP2 + ((size_t)(kt * 8 + p) * 131072 + m0g + m) * 16 + half * 8;
            __builtin_amdgcn_global_load_lds(AS1(g), AS3(&A_s[cid * 8]), 16, 0, 0);
        }
        __syncthreads();

#pragma unroll
        for (int kk = 0; kk < 4; ++kk) {
            int ckb = kk * 4 + quad;
            int p = ckb >> 1, hf = ckb & 1;
            short8 aq[4], bq[4];
#pragma unroll
            for (int t = 0; t < 4; ++t) {
                int m = m0 + t * 16 + ln_;
                aq[t] = *(const short8*)&A_s[p * 2048 + hf * 1024 + m * 8];
            }
#pragma unroll
            for (int t = 0; t < 4; ++t) {
                int wr = n0 + t * 16 + ln_;
                bq[t] = *(const short8*)(WOt2 + ((kt * 16 + ckb) * 128 + wr) * 8);
            }
#pragma unroll
            for (int mt = 0; mt < 4; ++mt)
#pragma unroll
                for (int nt = 0; nt < 4; ++nt)
                    acc[mt][nt] = __builtin_amdgcn_mfma_f32_16x16x32_bf16(aq[mt], bq[nt], acc[mt][nt], 0, 0, 0);
        }
    }

#pragma unroll
    for (int nt = 0; nt < 4; ++nt) {
        int ww = n0 + nt * 16 + ln_;
        float bo = bO[ww];
#pragma unroll
        for (int mt = 0; mt < 4; ++mt) {
            size_t mb = m0g + m0 + mt * 16 + quad * 4;
#pragma unroll
            for (int r = 0; r < 4; ++r)
                out[(mb + r) * 128 + ww] = acc[mt][nt][r] + bo;
        }
    }
}

// ---------------------------------------------------------------------------
extern "C" void kernel_launch(void* const* d_in, const int* in_sizes, int n_in,
                              void* d_out, int out_size, void* d_ws, size_t ws_size,
                              hipStream_t stream) {
    (void)in_sizes; (void)n_in; (void)out_size; (void)ws_size;
    const float* e    = (const float*)d_in[0];
    const float* mask = (const float*)d_in[1];
    const float* ln_g = (const float*)d_in[2];
    const float* ln_b = (const float*)d_in[3];
    const float* W_V  = (const float*)d_in[4];
    const float* b_V  = (const float*)d_in[5];
    const float* W_E  = (const float*)d_in[6];
    const float* b_E  = (const float*)d_in[7];
    const float* W_O  = (const float*)d_in[8];
    const float* b_O  = (const float*)d_in[9];
    float* out = (float*)d_out;

    char* ws = (char*)d_ws;
    short* VinT  = (short*)(ws + 0);           //  33,554,432 B
    short* VoutT = (short*)(ws + 33554432);    //  33,554,432 B
    short* Ain   = (short*)(ws + 67108864);    //   2,097,152 B
    short* AoutT = (short*)(ws + 69206016);    //   2,097,152 B
    short* VaP2  = (short*)(ws + 71303168);    //  67,108,864 B (aliases below)
    short* VoutU = (short*)(ws + 71303168);    //  33,554,432 B (inside VaP2)
    float* EoutR = (float*)(ws + 104857600);   //   8,388,608 B (inside VaP2)
    short* Wk    = (short*)(ws + 138412032);   //      69,632 B
    short* WOt2  = (short*)(ws + 138481664);   //      65,536 B
    float* bcat  = (float*)(ws + 138547200);   //       1,088 B

    k0_prep<<<49, 128, 0, stream>>>(W_V, W_E, W_O, Wk, WOt2, b_V, b_E, bcat);
    k1_ln_proj<<<dim3(256, 2), 256, 0, stream>>>(e, ln_g, ln_b, mask, Wk, bcat,
                                                 VinT, VoutU, Ain, EoutR);
    kT_transpose<<<dim3(4, 4, 256), 256, 0, stream>>>(VoutU, VoutT);
    k2_softmax_out<<<512, 256, 0, stream>>>(EoutR, mask, AoutT);
    k3_einsum<<<dim3(2, 32, 32), 256, 0, stream>>>(Ain, AoutT, VinT, VoutT, VaP2);
    k4_proj<<<1024, 256, 0, stream>>>(VaP2, WOt2, b_O, out);
}

// Round 7
// 225.267 us; speedup vs baseline: 1.8110x; 1.8110x over previous
//
#include <hip/hip_runtime.h>
#include <hip/hip_bf16.h>
#include <stdint.h>

// ---------------------------------------------------------------------------
// TripletAggregateUngated: B=2, N=256, W=128, H=8, D=16
//  K0: weight prep: Wcat2[2][144][128] bf16, WOt2[cc 32][wr 128][8] bf16,
//      bcat[2][144].
//  K1: (round-3 validated, 67 us) block = (b, fixed row, all 256 k), full
//      256x128 A-tile, V stored direct from acc as 128-B-per-wave runs,
//      in-block softmax.
//  K3: einsum batched GEMMs BK=64 x4; NEW: C staged to LDS, cooperative
//      full-line VaP2 stores (each 128-B line from consecutive lanes).
//  K4: Va @ W_O; NEW tiling: wave owns full 128-w width so each out row's
//      512 B is written by one wave in consecutive instructions.
// Rule learned R3/R5/R6: every global store pattern must complete 128-B lines
// within one wave's consecutive instructions, else L2 partial-line RMW
// inflates FETCH+WRITE by 2-4x.
// ---------------------------------------------------------------------------

typedef short short8 __attribute__((ext_vector_type(8)));
typedef short short4v __attribute__((ext_vector_type(4)));
typedef float floatx4 __attribute__((ext_vector_type(4)));

#define AS1(p) ((const __attribute__((address_space(1))) void*)(p))
#define AS3(p) ((__attribute__((address_space(3))) void*)(p))

__device__ inline short f2bf(float v) {
    uint32_t u = __builtin_bit_cast(uint32_t, v);
    u += 0x7FFFu + ((u >> 16) & 1u);   // RNE; inputs finite
    return (short)(u >> 16);
}

// ---------------------------------------------------------------------------
// K0: weight/bias prep.
// ---------------------------------------------------------------------------
__global__ __launch_bounds__(128) void k0_prep(const float* __restrict__ WV,
                                               const float* __restrict__ WE,
                                               const float* __restrict__ WO,
                                               short* __restrict__ Wcat2,
                                               short* __restrict__ WOt2,
                                               const float* __restrict__ bV,
                                               const float* __restrict__ bE,
                                               float* __restrict__ bcat) {
    int bx = blockIdx.x, t = threadIdx.x;
    if (bx < 288) {
        int v = bx / 144, n = bx % 144, k = t;
        float val = 0.f;
        if (n < 128) val = WV[k * 256 + v * 128 + n];
        else if (n < 136) val = WE[k * 16 + v * 8 + (n - 128)];
        Wcat2[(v * 144 + n) * 128 + k] = f2bf(val);
    } else if (bx < 320) {
        int cc = bx - 288;
        for (int j = 0; j < 8; ++j) {
            int c = cc * 8 + j;
            WOt2[(cc * 128 + t) * 8 + j] =
                f2bf(WO[((c & 15) * 16 + (c >> 4)) * 128 + t]);
        }
    } else {
        for (int it = 0; it < 3; ++it) {
            int idx = it * 128 + t;
            if (idx < 288) {
                int v = idx / 144, n = idx % 144;
                float val = 0.f;
                if (n < 128) val = bV[v * 128 + n];
                else if (n < 136) val = bE[v * 8 + (n - 128)];
                bcat[idx] = val;
            }
        }
    }
}

// ---------------------------------------------------------------------------
// K1 (round-3 validated): fused LN + projection + softmax.
// blockIdx: x = fixed row (256), y = b (2), z = variant v (2).
//  v=0: fix=i, k=r2 -> V_in + E_in softmax; v=1: fix=j, k=r1 -> V_out + E_out.
// At: 256 rows x 128 cols bf16, granule g stored at position g ^ (row & 15).
// ---------------------------------------------------------------------------
__global__ __launch_bounds__(256, 2) void k1_ln_proj(
    const float* __restrict__ e, const float* __restrict__ ln_g,
    const float* __restrict__ ln_b, const float* __restrict__ mask,
    const short* __restrict__ Wcat2, const float* __restrict__ bcat,
    short* __restrict__ VinT, short* __restrict__ VoutT,
    short* __restrict__ Ain, short* __restrict__ AoutT) {
    __shared__ short At[256 * 128];   // 64 KB
    __shared__ float maskb[256];
    __shared__ float redm[4][8];
    __shared__ float reds[4][8];

    const int tid = threadIdx.x;
    const int fix = blockIdx.x;
    const int b = blockIdx.y;
    const int v = blockIdx.z;
    const int estride = v ? 256 : 1;
    const size_t ebase = (size_t)b * 65536 + (size_t)fix * (v ? 1 : 256);
    const short* Wv = Wcat2 + v * 144 * 128;
    const float* bc = bcat + v * 144;
    short* Vdst = v ? VoutT : VinT;
    short* Adst = v ? AoutT : Ain;

    maskb[tid] = mask[(size_t)b * 65536 + (v ? (size_t)tid * 256 + fix
                                             : (size_t)fix * 256 + tid)];

    // LayerNorm: 4 threads/row, 4 passes over rows.
    {
        const int rq = tid & 3;
        const int rowi = tid >> 2;
#pragma unroll
        for (int pass = 0; pass < 4; ++pass) {
            int row = pass * 64 + rowi;
            const float* ep = e + (ebase + (size_t)row * estride) * 128 + rq * 4;
            float4 val[8];
            float s = 0.f, s2 = 0.f;
#pragma unroll
            for (int i = 0; i < 8; ++i) {
                val[i] = *(const float4*)(ep + i * 16);
                s += val[i].x + val[i].y + val[i].z + val[i].w;
                s2 += val[i].x * val[i].x + val[i].y * val[i].y +
                      val[i].z * val[i].z + val[i].w * val[i].w;
            }
            s += __shfl_xor(s, 1); s2 += __shfl_xor(s2, 1);
            s += __shfl_xor(s, 2); s2 += __shfl_xor(s2, 2);
            float mean = s * 0.0078125f;
            float var = s2 * 0.0078125f - mean * mean;
            float rs = rsqrtf(var + 1e-5f);
#pragma unroll
            for (int i = 0; i < 8; ++i) {
                int col = i * 16 + rq * 4;
                float4 gg = *(const float4*)(ln_g + col);
                float4 bb = *(const float4*)(ln_b + col);
                short4v o;
                o[0] = f2bf((val[i].x - mean) * rs * gg.x + bb.x);
                o[1] = f2bf((val[i].y - mean) * rs * gg.y + bb.y);
                o[2] = f2bf((val[i].z - mean) * rs * gg.z + bb.z);
                o[3] = f2bf((val[i].w - mean) * rs * gg.w + bb.w);
                int g = col >> 3;
                int cp = g ^ (row & 15);
                int half = (col >> 2) & 1;
                *(short4v*)&At[row * 128 + cp * 8 + half * 4] = o;
            }
        }
    }
    __syncthreads();

    const int lane = tid & 63, w = tid >> 6;
    const int ln_ = lane & 15, quad = lane >> 4;
    float vE[16];

    // ---- V chunks: wave w owns k-rows w*64..w*64+63 (4 m-subtiles) ----
#pragma unroll
    for (int chunk = 0; chunk < 2; ++chunk) {
        floatx4 acc[4][4] = {};
#pragma unroll
        for (int kk = 0; kk < 4; ++kk) {
            int ckb = kk * 4 + quad;
            int cp = ckb ^ ln_;
            short8 aq[4];
#pragma unroll
            for (int mt = 0; mt < 4; ++mt) {
                int r = w * 64 + mt * 16 + ln_;
                aq[mt] = *(const short8*)&At[r * 128 + cp * 8];
            }
            short8 bq[4];
#pragma unroll
            for (int ntl = 0; ntl < 4; ++ntl) {
                int n = chunk * 64 + ntl * 16 + ln_;
                bq[ntl] = *(const short8*)(Wv + n * 128 + ckb * 8);
            }
#pragma unroll
            for (int mt = 0; mt < 4; ++mt)
#pragma unroll
                for (int ntl = 0; ntl < 4; ++ntl)
                    acc[mt][ntl] = __builtin_amdgcn_mfma_f32_16x16x32_bf16(
                        aq[mt], bq[ntl], acc[mt][ntl], 0, 0, 0);
        }
#pragma unroll
        for (int ntl = 0; ntl < 4; ++ntl) {
            int c = chunk * 64 + ntl * 16 + ln_;
            float bias = bc[c];
            int d = c >> 3, hh = c & 7;
            size_t rowbase = (((size_t)(b * 8 + hh) * 256 + fix) * 16 + d) * 256;
#pragma unroll
            for (int mt = 0; mt < 4; ++mt) {
                short4v o;
#pragma unroll
                for (int r = 0; r < 4; ++r) o[r] = f2bf(acc[mt][ntl][r] + bias);
                *(short4v*)(Vdst + rowbase + w * 64 + mt * 16 + quad * 4) = o;
            }
        }
    }

    // ---- E chunk: cols 128..143 (8 real + 8 pad) ----
    {
        floatx4 accE[4] = {};
#pragma unroll
        for (int kk = 0; kk < 4; ++kk) {
            int ckb = kk * 4 + quad;
            int cp = ckb ^ ln_;
            short8 bq = *(const short8*)(Wv + (128 + ln_) * 128 + ckb * 8);
#pragma unroll
            for (int mt = 0; mt < 4; ++mt) {
                int r = w * 64 + mt * 16 + ln_;
                short8 aq = *(const short8*)&At[r * 128 + cp * 8];
                accE[mt] = __builtin_amdgcn_mfma_f32_16x16x32_bf16(
                    aq, bq, accE[mt], 0, 0, 0);
            }
        }
        float bias = bc[128 + ln_];
#pragma unroll
        for (int mt = 0; mt < 4; ++mt)
#pragma unroll
            for (int r = 0; r < 4; ++r) {
                int k = w * 64 + mt * 16 + quad * 4 + r;
                vE[mt * 4 + r] = accE[mt][r] + bias + maskb[k];
            }
    }

    // ---- softmax over the 16 k-values per (lane-col, wave) ----
    {
        float m = vE[0];
#pragma unroll
        for (int i = 1; i < 16; ++i) m = fmaxf(m, vE[i]);
        m = fmaxf(m, __shfl_xor(m, 16));
        m = fmaxf(m, __shfl_xor(m, 32));
        if (quad == 0 && ln_ < 8) redm[w][ln_] = m;
        __syncthreads();
        int hs = ln_ & 7;
        float bmax = fmaxf(fmaxf(redm[0][hs], redm[1][hs]),
                           fmaxf(redm[2][hs], redm[3][hs]));
        float p[16], s = 0.f;
#pragma unroll
        for (int i = 0; i < 16; ++i) { p[i] = __expf(vE[i] - bmax); s += p[i]; }
        s += __shfl_xor(s, 16);
        s += __shfl_xor(s, 32);
        if (quad == 0 && ln_ < 8) reds[w][ln_] = s;
        __syncthreads();
        float inv = 1.f / (reds[0][hs] + reds[1][hs] + reds[2][hs] + reds[3][hs]);
        if (ln_ < 8) {
            size_t rowbase = (size_t)(b * 8 + ln_) * 65536 + (size_t)fix * 256;
#pragma unroll
            for (int mt = 0; mt < 4; ++mt) {
                short4v o;
#pragma unroll
                for (int r = 0; r < 4; ++r) o[r] = f2bf(p[mt * 4 + r] * inv);
                *(short4v*)(Adst + rowbase + w * 64 + mt * 16 + quad * 4) = o;
            }
        }
    }
}

// ---------------------------------------------------------------------------
// K3: per (b,h,part): C[i,jd] = sum_k A[i,k] V[jd,k]. 128x128 tile, BK=64 x4.
// K-loop LDS: chunks [0,1024) A, [1024,2048) B (first 32 KB of AB).
// Epilogue: C staged in AB at row stride 136, then cooperative stores so each
// VaP2 128-B line is written by consecutive lanes of one wave.
// ---------------------------------------------------------------------------
__global__ __launch_bounds__(256, 3) void k3_einsum(const short* __restrict__ Ain,
                                                    const short* __restrict__ AoutT,
                                                    const short* __restrict__ VinT,
                                                    const short* __restrict__ VoutT,
                                                    short* __restrict__ VaP2) {
    __shared__ short AB[17408];  // 34,816 B (K-loop uses first 16384 shorts)
    const int tid = threadIdx.x, lane = tid & 63, w = tid >> 6;
    const int i0 = blockIdx.x * 128;
    const int jd0 = blockIdx.y * 128;
    const int z = blockIdx.z;
    const int b = z >> 4, part = (z >> 3) & 1, h = z & 7;

    const short* Abase = (part ? AoutT : Ain) + ((size_t)(b * 8 + h)) * 65536 + (size_t)i0 * 256;
    const short* Bbase = (part ? VoutT : VinT) + ((size_t)(b * 8 + h)) * 1048576 + (size_t)jd0 * 256;

    const int ln_ = lane & 15, quad = lane >> 4;
    const int m0 = (w >> 1) * 64, n0 = (w & 1) * 64;
    floatx4 acc[4][4] = {};

    for (int kt = 0; kt < 4; ++kt) {
        if (kt) __syncthreads();
        for (int it = 0; it < 8; ++it) {
            int cid = w * 512 + it * 64 + lane;   // 0..2047
            int isB = cid >> 10;
            int lc = cid & 1023;
            int r = lc >> 3;
            int ck = (lc & 7) ^ (r & 7);
            const short* g = (isB ? Bbase : Abase) + r * 256 + kt * 64 + ck * 8;
            __builtin_amdgcn_global_load_lds(AS1(g), AS3(&AB[cid * 8]), 16, 0, 0);
        }
        __syncthreads();

#pragma unroll
        for (int kk = 0; kk < 2; ++kk) {
            int ckb = kk * 4 + quad;
            short8 aq[4], bq[4];
#pragma unroll
            for (int t = 0; t < 4; ++t) {
                int r = m0 + t * 16 + ln_;
                aq[t] = *(const short8*)&AB[(r * 8 + (ckb ^ (r & 7))) * 8];
            }
#pragma unroll
            for (int t = 0; t < 4; ++t) {
                int r = n0 + t * 16 + ln_;
                bq[t] = *(const short8*)&AB[(1024 + r * 8 + (ckb ^ (r & 7))) * 8];
            }
#pragma unroll
            for (int mt = 0; mt < 4; ++mt)
#pragma unroll
                for (int nt = 0; nt < 4; ++nt)
                    acc[mt][nt] = __builtin_amdgcn_mfma_f32_16x16x32_bf16(aq[mt], bq[nt], acc[mt][nt], 0, 0, 0);
        }
    }

    // ---- epilogue: stage C tile (128 x 128 bf16, stride 136) ----
    __syncthreads();   // all AB reads done
#pragma unroll
    for (int mt = 0; mt < 4; ++mt)
#pragma unroll
        for (int nt = 0; nt < 4; ++nt)
#pragma unroll
            for (int r = 0; r < 4; ++r) {
                int il = m0 + mt * 16 + quad * 4 + r;
                int jd = n0 + nt * 16 + ln_;
                AB[il * 136 + jd] = f2bf(acc[mt][nt][r]);
            }
    __syncthreads();

    const int ph = part * 8 + h;
    const int j0 = jd0 >> 4;
#pragma unroll
    for (int pp = 0; pp < 4; ++pp) {
        int pid = pp * 256 + tid;      // 0..1023
        int il = pid >> 3, jl = pid & 7;
        size_t m = ((size_t)b * 256 + i0 + il) * 256 + j0 + jl;
        short8 v0 = *(const short8*)&AB[il * 136 + jl * 16];
        short8 v1 = *(const short8*)&AB[il * 136 + jl * 16 + 8];
        short* dst = VaP2 + ((size_t)ph * 131072 + m) * 16;
        *(short8*)dst = v0;
        *(short8*)(dst + 8) = v1;
    }
}

// ---------------------------------------------------------------------------
// K4: out[m][w] = sum_c A[m][c] * WOt2[cc][w][8] + bO[w].
// Wave owns m0=w*32 (2 m-subtiles) x FULL 128-w width (acc[2][8]) so each
// out row's 512 B is stored by one wave in 8 consecutive instructions.
// ---------------------------------------------------------------------------
__global__ __launch_bounds__(256, 3) void k4_proj(const short* __restrict__ VaP2,
                                                  const short* __restrict__ WOt2,
                                                  const float* __restrict__ bO,
                                                  float* __restrict__ out) {
    __shared__ short A_s[16384];  // 32 KB
    const int tid = threadIdx.x, lane = tid & 63, w = tid >> 6;
    const size_t m0g = (size_t)blockIdx.x * 128;
    const int ln_ = lane & 15, quad = lane >> 4;
    const int m0 = w * 32;
    floatx4 acc[2][8] = {};

    for (int kt = 0; kt < 2; ++kt) {
        if (kt) __syncthreads();
        for (int it = 0; it < 8; ++it) {
            int cid = w * 512 + it * 64 + lane;     // 0..2047
            int p = cid >> 8, rm = cid & 255, half = rm >> 7, m = rm & 127;
            const short* g = VaP2 + ((size_t)(kt * 8 + p) * 131072 + m0g + m) * 16 + half * 8;
            __builtin_amdgcn_global_load_lds(AS1(g), AS3(&A_s[cid * 8]), 16, 0, 0);
        }
        __syncthreads();

#pragma unroll
        for (int kk = 0; kk < 4; ++kk) {
            int ckb = kk * 4 + quad;
            int p = ckb >> 1, hf = ckb & 1;
            short8 aq[2], bq[8];
#pragma unroll
            for (int mt = 0; mt < 2; ++mt) {
                int m = m0 + mt * 16 + ln_;
                aq[mt] = *(const short8*)&A_s[p * 2048 + hf * 1024 + m * 8];
            }
#pragma unroll
            for (int nt = 0; nt < 8; ++nt) {
                int wr = nt * 16 + ln_;
                bq[nt] = *(const short8*)(WOt2 + ((kt * 16 + ckb) * 128 + wr) * 8);
            }
#pragma unroll
            for (int mt = 0; mt < 2; ++mt)
#pragma unroll
                for (int nt = 0; nt < 8; ++nt)
                    acc[mt][nt] = __builtin_amdgcn_mfma_f32_16x16x32_bf16(aq[mt], bq[nt], acc[mt][nt], 0, 0, 0);
        }
    }

    float bo[8];
#pragma unroll
    for (int nt = 0; nt < 8; ++nt) bo[nt] = bO[nt * 16 + ln_];

#pragma unroll
    for (int mt = 0; mt < 2; ++mt)
#pragma unroll
        for (int r = 0; r < 4; ++r) {
            size_t mb = m0g + m0 + mt * 16 + quad * 4 + r;
#pragma unroll
            for (int nt = 0; nt < 8; ++nt)
                out[mb * 128 + nt * 16 + ln_] = acc[mt][nt][r] + bo[nt];
        }
}

// ---------------------------------------------------------------------------
extern "C" void kernel_launch(void* const* d_in, const int* in_sizes, int n_in,
                              void* d_out, int out_size, void* d_ws, size_t ws_size,
                              hipStream_t stream) {
    (void)in_sizes; (void)n_in; (void)out_size; (void)ws_size;
    const float* e    = (const float*)d_in[0];
    const float* mask = (const float*)d_in[1];
    const float* ln_g = (const float*)d_in[2];
    const float* ln_b = (const float*)d_in[3];
    const float* W_V  = (const float*)d_in[4];
    const float* b_V  = (const float*)d_in[5];
    const float* W_E  = (const float*)d_in[6];
    const float* b_E  = (const float*)d_in[7];
    const float* W_O  = (const float*)d_in[8];
    const float* b_O  = (const float*)d_in[9];
    float* out = (float*)d_out;

    char* ws = (char*)d_ws;
    short* VinT  = (short*)(ws + 0);           //  33,554,432 B
    short* VoutT = (short*)(ws + 33554432);    //  33,554,432 B
    short* Ain   = (short*)(ws + 67108864);    //   2,097,152 B
    short* AoutT = (short*)(ws + 69206016);    //   2,097,152 B
    short* VaP2  = (short*)(ws + 71303168);    //  67,108,864 B
    short* Wcat2 = (short*)(ws + 138412032);   //      73,728 B
    short* WOt2  = (short*)(ws + 138485760);   //      65,536 B
    float* bcat  = (float*)(ws + 138551296);   //       1,152 B

    k0_prep<<<321, 128, 0, stream>>>(W_V, W_E, W_O, Wcat2, WOt2, b_V, b_E, bcat);
    k1_ln_proj<<<dim3(256, 2, 2), 256, 0, stream>>>(e, ln_g, ln_b, mask, Wcat2,
                                                    bcat, VinT, VoutT, Ain, AoutT);
    k3_einsum<<<dim3(2, 32, 32), 256, 0, stream>>>(Ain, AoutT, VinT, VoutT, VaP2);
    k4_proj<<<1024, 256, 0, stream>>>(VaP2, WOt2, b_O, out);
}